// Round 2
// baseline (89.834 us; speedup 1.0000x reference)
//
#include <hip/hip_runtime.h>

// VQ-VAE quantizer: x[32][64][64][64] f32 NCHW, embed[1024][64] f32
// out: z_q (8388608 f32, NCHW) ++ loss (1 f32)
// loss = 1.25 * mean((z_q - z)^2)

#define TOTAL_ELEMS 8388608
#define LOSS_SCALE (1.25f / 8388608.f)

typedef float  f32x4  __attribute__((ext_vector_type(4)));
typedef __bf16 bf16x8 __attribute__((ext_vector_type(8)));
typedef unsigned int u32x4 __attribute__((ext_vector_type(4)));

static __device__ __forceinline__ unsigned short f2bf(float f) {
    unsigned int u = __float_as_uint(f);
    u += 0x7FFFu + ((u >> 16) & 1u);   // round-to-nearest-even
    return (unsigned short)(u >> 16);
}

// ---- prep: embed f32 -> bf16 copy + c0 = 0.25 - 0.5*||e||^2 + zero loss ----
// grid 16 x 256: 4 threads per embed row
__global__ void vq_prep(const float* __restrict__ embed,
                        unsigned short* __restrict__ eb,
                        float* __restrict__ c0,
                        float* __restrict__ loss_slot) {
    int t   = blockIdx.x * 256 + threadIdx.x;   // 0..4095
    int row = t >> 2, qd = t & 3;
    const float* src = embed + row * 64 + qd * 16;
    float s = 0.f;
    unsigned short tmp[16];
#pragma unroll
    for (int i = 0; i < 4; i++) {
        f32x4 v = *(const f32x4*)(src + i * 4);
#pragma unroll
        for (int j = 0; j < 4; j++) {
            float f = v[j];
            s += f * f;
            tmp[i * 4 + j] = f2bf(f);
        }
    }
    u32x4 w0, w1;
#pragma unroll
    for (int i = 0; i < 4; i++) {
        w0[i] = (unsigned)tmp[2*i]     | ((unsigned)tmp[2*i+1] << 16);
        w1[i] = (unsigned)tmp[8+2*i]   | ((unsigned)tmp[8+2*i+1] << 16);
    }
    u32x4* dst = (u32x4*)(eb + row * 64 + qd * 16);
    dst[0] = w0; dst[1] = w1;
    // reduce sumsq across the 4 threads sharing a row (same wave)
    s += __shfl_xor(s, 1);
    s += __shfl_xor(s, 2);
    if (qd == 0) c0[row] = 0.25f - 0.5f * s;    // MFMA C-init: acc = z.e + c0 > 0
    if (t == 0) *loss_slot = 0.f;
}

// ---- main fused kernel ----
// block = 256 threads = 4 waves; one block per (b,h): 64 positions (w) x 64 channels
// wave wv handles codes [wv*256, wv*256+256)
// argmin dist == argmax acc (acc = z.e + 0.25 - ||e||^2/2, strictly positive)
// key = (bits(acc) & ~1023) | (1023 - code)  -> single v_max_u32 chain
__global__ __launch_bounds__(256, 2) void vq_main(
    const float* __restrict__ x,
    const float* __restrict__ embed,            // f32, for exact gather
    const unsigned short* __restrict__ eb,      // bf16
    const float* __restrict__ c0,               // f32 per-code C-init
    float* __restrict__ out,
    float* __restrict__ loss) {

    __shared__ unsigned short tile[64 * 64];    // [pos][k] bf16, XOR-swizzled, 8 KB
    __shared__ unsigned int wkey[4][64];
    __shared__ int   idxf[64];
    __shared__ float lpart[4];

    const int t   = threadIdx.x;
    const int blk = blockIdx.x;                 // 0..2047
    const int b   = blk >> 6, h = blk & 63;
    const size_t base = (size_t)b * 262144 + (size_t)h * 64;  // x[b][0][h][0]

    const int wv = t >> 6, lane = t & 63;
    const int l15 = lane & 15, lq = lane >> 4;  // lq: 0..3
    const int k0 = lq * 8;
    const int cb = wv * 256;

    // ---- stage Z tile into LDS (transpose [c][w] -> [w][c], f32 -> bf16) ----
    const int c = t & 63, q = t >> 6;           // q uniform within a wave
#pragma unroll
    for (int i = 0; i < 4; i++) {
        int w0 = q * 16 + i * 4;
        f32x4 v = *(const f32x4*)(x + base + (size_t)c * 4096 + w0);
#pragma unroll
        for (int j = 0; j < 4; j++) {
            int w = w0 + j;
            int byteoff = w * 128 + ((c * 2) ^ ((w & 7) << 4));
            *(unsigned short*)((char*)tile + byteoff) = f2bf(v[j]);
        }
    }

    // ---- prefetch mt=0 A-frags before the barrier (HBM stage wait hides L2 lat) ----
    bf16x8 pa0[2], pa1[2];
    f32x4  pc0[2];
    {
        int mrow = cb + l15;
        pa0[0] = *(const bf16x8*)(eb + mrow * 64 + k0);
        pa1[0] = *(const bf16x8*)(eb + mrow * 64 + 32 + k0);
        pc0[0] = *(const f32x4*)(c0 + cb + lq * 4);
    }
    __syncthreads();

    // ---- B-frags: Z for 4 position-tiles x 2 K-halves ----
    bf16x8 bfr[4][2];
#pragma unroll
    for (int nt = 0; nt < 4; nt++) {
        int pos = nt * 16 + l15;
        int rb  = pos * 128;
        int sw  = (pos & 7) << 4;
        bfr[nt][0] = *(const bf16x8*)((const char*)tile + rb + ((k0 * 2) ^ sw));
        bfr[nt][1] = *(const bf16x8*)((const char*)tile + rb + ((64 + k0 * 2) ^ sw));
    }

    // ---- MFMA + packed-key argmax, depth-2 software pipeline over mt ----
    unsigned int key[4] = {0u, 0u, 0u, 0u};
    const int inv_base = 1023 - cb - lq * 4;    // per-lane; minus mt*16 + r below

#pragma unroll
    for (int mt = 0; mt < 16; mt++) {
        const int cur = mt & 1, nxt = cur ^ 1;
        if (mt < 15) {                           // prefetch mt+1
            int mrow = cb + (mt + 1) * 16 + l15;
            pa0[nxt] = *(const bf16x8*)(eb + mrow * 64 + k0);
            pa1[nxt] = *(const bf16x8*)(eb + mrow * 64 + 32 + k0);
            pc0[nxt] = *(const f32x4*)(c0 + cb + (mt + 1) * 16 + lq * 4);
        }
        const int invm = inv_base - mt * 16;
#pragma unroll
        for (int nt = 0; nt < 4; nt++) {
            f32x4 acc = __builtin_amdgcn_mfma_f32_16x16x32_bf16(pa0[cur], bfr[nt][0], pc0[cur], 0, 0, 0);
            acc = __builtin_amdgcn_mfma_f32_16x16x32_bf16(pa1[cur], bfr[nt][1], acc, 0, 0, 0);
            // D: col(l15)=pos-in-tile, row=(lq*4+r)=code-in-chunk
#pragma unroll
            for (int r = 0; r < 4; r++) {
                unsigned int k2 = (__float_as_uint(acc[r]) & 0xFFFFFC00u)
                                | (unsigned int)(invm - r);
                key[nt] = key[nt] > k2 ? key[nt] : k2;
            }
        }
    }

    // ---- wave-level argmax reduce (code chunks spread over lane^16, lane^32) ----
#pragma unroll
    for (int nt = 0; nt < 4; nt++) {
        unsigned int k = key[nt];
        unsigned int o = (unsigned int)__shfl_xor((int)k, 16); k = k > o ? k : o;
        o = (unsigned int)__shfl_xor((int)k, 32);              k = k > o ? k : o;
        if (lane < 16) wkey[wv][nt * 16 + lane] = k;
    }
    __syncthreads();

    // ---- cross-wave combine: thread t<64 -> final idx for position t ----
    if (t < 64) {
        unsigned int k = wkey[0][t];
        unsigned int o1 = wkey[1][t]; k = k > o1 ? k : o1;
        unsigned int o2 = wkey[2][t]; k = k > o2 ? k : o2;
        unsigned int o3 = wkey[3][t]; k = k > o3 ? k : o3;
        idxf[t] = 1023 - (int)(k & 1023u);
    }
    __syncthreads();

    // ---- output: gather z_q (exact f32), write NCHW, loss partial ----
    float ls = 0.f;
#pragma unroll
    for (int i = 0; i < 4; i++) {
        int w0 = q * 16 + i * 4;
        const size_t off = base + (size_t)c * 4096 + w0;
        f32x4 xv = *(const f32x4*)(x + off);   // L1-hot re-read (exact z for loss)
        f32x4 ov;
#pragma unroll
        for (int j = 0; j < 4; j++) {
            int idx = idxf[w0 + j];            // uniform across wave -> coalesced gather
            float zq = embed[idx * 64 + c];
            ov[j] = zq;
            float d = zq - xv[j];
            ls += d * d;
        }
        *(f32x4*)(out + off) = ov;
    }

    // block-reduce loss, one atomic per block
#pragma unroll
    for (int off = 1; off < 64; off <<= 1) ls += __shfl_xor(ls, off);
    if (lane == 0) lpart[wv] = ls;
    __syncthreads();
    if (t == 0) {
        float s = lpart[0] + lpart[1] + lpart[2] + lpart[3];
        atomicAdd(loss, s * LOSS_SCALE);
    }
}

extern "C" void kernel_launch(void* const* d_in, const int* in_sizes, int n_in,
                              void* d_out, int out_size, void* d_ws, size_t ws_size,
                              hipStream_t stream) {
    const float* x     = (const float*)d_in[0];
    const float* embed = (const float*)d_in[1];
    unsigned short* eb = (unsigned short*)d_ws;               // 1024*64 bf16 = 128 KB
    float* c0          = (float*)((char*)d_ws + 131072);      // 1024 f32  = 4 KB
    float* out  = (float*)d_out;
    float* loss = out + TOTAL_ELEMS;

    vq_prep<<<16, 256, 0, stream>>>(embed, eb, c0, loss);
    vq_main<<<2048, 256, 0, stream>>>(x, embed, eb, c0, out, loss);
}